// Round 10
// baseline (1442.761 us; speedup 1.0000x reference)
//
#include <hip/hip_runtime.h>
#include <hip/hip_bf16.h>
#include <math.h>

typedef unsigned short u16;
typedef unsigned int   u32;
typedef unsigned long long u64;

#define DEV static __device__ __forceinline__

static constexpr int LL = 128, DD = 512, HH = 256, KK = 5, NN = 1024;

// workspace byte offsets
static constexpr size_t OFF_QP   = 0;        // 512 f32
static constexpr size_t OFF_U    = 4096;     // 512 f32
static constexpr size_t OFF_CC   = 8192;     // 1 f32
static constexpr size_t OFF_SC   = 12288;    // 1024 f32
static constexpr size_t OFF_WSC  = 16384;    // 5 f32
static constexpr size_t OFF_IDX  = 16640;    // 5 int
static constexpr size_t OFF_HG   = 20480;    // [2 layers][2 dir][2 parity][5][256] f32 = 40960B
static constexpr size_t OFF_FLG0 = 61440;    // layer0 flags (dir stride 256B)
static constexpr size_t OFF_FLG1 = 65536;    // layer1 flags
static constexpr size_t OFF_CNT  = 69632;    // 3 ints: front-end phase counters
static constexpr size_t OFF_PRE  = 73728;    // [2][128][5][1024] f32 = 5242880B
static constexpr size_t OFF_OUT0 = OFF_PRE  + (size_t)2*LL*5*1024*4;
static constexpr size_t OFF_OUT1 = OFF_OUT0 + (size_t)5*LL*DD*4;

DEV float sigf(float x){ return 1.0f/(1.0f + expf(-x)); }

DEV float ald(const float* p) {
  return __hip_atomic_load(p, __ATOMIC_RELAXED, __HIP_MEMORY_SCOPE_AGENT);
}
DEV void ast(float* p, float v) {
  __hip_atomic_store(p, v, __ATOMIC_RELAXED, __HIP_MEMORY_SCOPE_AGENT);
}
template<int SLP>
DEV void wait_ge(int* p, int v) {
  while (__hip_atomic_load(p, __ATOMIC_RELAXED, __HIP_MEMORY_SCOPE_AGENT) < v)
    __builtin_amdgcn_s_sleep(SLP);
}

// ---------------- fused front-end: qproj -> keyvec -> scores -> topk ----------
// 1024 blocks x 256 thr, ALL co-resident (4 blocks/CU exactly fits).
// CROSS-BLOCK DATA (qp,u,cconst,scores) must be published via agent-scope
// atomic stores (write-through to coherent point) — plain stores sit dirty in
// the writer XCD's L2 and agent-scope readers see stale values (G16).
// That was the R9 correctness bug.
__global__ __launch_bounds__(256) void k_front(
    const float* __restrict__ Wq, const float* __restrict__ qu,
    const float* __restrict__ bq, const float* __restrict__ Wk,
    const float* __restrict__ bk, const float* __restrict__ ep,
    const float* __restrict__ ages,
    float* __restrict__ qp, float* __restrict__ u, float* __restrict__ cconst,
    float* __restrict__ scores, int* __restrict__ idx5, float* __restrict__ wsc,
    int* __restrict__ cnt) {
  __shared__ float qs[512];
  __shared__ float red2[16][17];
  __shared__ float r2[256];
  __shared__ float redS[256];
  __shared__ float s0[NN];
  __shared__ float sv[256];
  __shared__ int   si[256];
  __shared__ int   chosen[KK];
  int bid = blockIdx.x, tid = threadIdx.x;

  // ---- phase A: qproj (blocks 0..63: 8 rows each, 32 lanes/row) ----
  if (bid < 64) {
    qs[tid] = qu[tid]; qs[tid+256] = qu[tid+256];
    __syncthreads();
    int row = bid*8 + (tid >> 5), lane = tid & 31;
    const float* wr = Wq + (size_t)row*512 + lane*16;
    float acc = 0.f;
    #pragma unroll
    for (int j = 0; j < 16; j += 4) {
      float4 w = *(const float4*)(wr + j);
      acc += w.x*qs[lane*16+j] + w.y*qs[lane*16+j+1] + w.z*qs[lane*16+j+2] + w.w*qs[lane*16+j+3];
    }
    #pragma unroll
    for (int off = 16; off > 0; off >>= 1) acc += __shfl_down(acc, off, 32);
    if (lane == 0) ast(&qp[row], acc + bq[row]);
    __syncthreads();                    // vmcnt drain: qp stores acked at IF
    if (tid == 0) __hip_atomic_fetch_add(&cnt[0], 1, __ATOMIC_RELAXED, __HIP_MEMORY_SCOPE_AGENT);
    __syncthreads();
  }

  // ---- phase B: keyvec (blocks 64..95: 16 cols each) ----
  if (bid >= 64 && bid < 96) {
    if (tid == 0) wait_ge<2>(&cnt[0], 64);
    __syncthreads();
    qs[tid] = ald(&qp[tid]); qs[tid+256] = ald(&qp[tid+256]);
    __syncthreads();
    int kb = bid - 64;
    int cl = tid & 15, jc = tid >> 4;
    int col = kb*16 + cl;
    float acc = 0.f;
    for (int j = jc*32; j < jc*32 + 32; ++j) acc += Wk[(size_t)j*512 + col] * qs[j];
    red2[cl][jc] = acc;
    __syncthreads();
    if (tid < 16) {
      float a = 0.f;
      #pragma unroll
      for (int m = 0; m < 16; ++m) a += red2[tid][m];
      ast(&u[kb*16 + tid], a);
    }
    if (kb == 0) {
      float b2 = bk[tid]*qs[tid] + bk[tid+256]*qs[tid+256];
      r2[tid] = b2;
      __syncthreads();
      for (int off = 128; off > 0; off >>= 1) { if (tid < off) r2[tid] += r2[tid+off]; __syncthreads(); }
      if (tid == 0) ast(&cconst[0], r2[0]);
    }
    __syncthreads();                    // u (+cconst) stores acked at IF
    if (tid == 0) __hip_atomic_fetch_add(&cnt[1], 1, __ATOMIC_RELAXED, __HIP_MEMORY_SCOPE_AGENT);
    __syncthreads();
  }

  // ---- phase C: scores (all 1024 blocks, n = bid) ----
  {
    if (tid == 0) wait_ge<32>(&cnt[1], 32);
    __syncthreads();
    int d0 = (tid * 4) & 511;
    float u0 = ald(&u[d0+0]), u1 = ald(&u[d0+1]), u2 = ald(&u[d0+2]), u3 = ald(&u[d0+3]);
    float ccv = ald(cconst);
    const float* base = ep + (size_t)bid * (LL*DD);
    float acc = 0.f;
    for (int c = tid; c < (LL*DD)/4; c += 256) {
      float4 v = *(const float4*)(base + (size_t)c*4);
      acc += v.x*u0 + v.y*u1 + v.z*u2 + v.w*u3;
    }
    redS[tid] = acc;
    __syncthreads();
    for (int off = 128; off > 0; off >>= 1) { if (tid < off) redS[tid] += redS[tid+off]; __syncthreads(); }
    if (tid == 0) ast(&scores[bid], redS[0] * (1.0f/LL) + ccv);
    __syncthreads();                    // scores store acked at IF
    if (tid == 0) __hip_atomic_fetch_add(&cnt[2], 1, __ATOMIC_RELAXED, __HIP_MEMORY_SCOPE_AGENT);
  }

  // ---- phase D: topk (block 0 only) ----
  if (bid == 0) {
    if (tid == 0) wait_ge<8>(&cnt[2], NN);
    __syncthreads();
    #pragma unroll
    for (int k = 0; k < 4; ++k) s0[tid + k*256] = ald(&scores[tid + k*256]);
    __syncthreads();
    for (int r = 0; r < KK; ++r) {
      float bv = -3.4e38f; int bi = 0x7fffffff;
      #pragma unroll
      for (int k = 0; k < 4; ++k) {
        int i = tid + k*256;
        float v = s0[i];
        bool excl = false;
        for (int m = 0; m < r; ++m) excl = excl || (chosen[m] == i);
        if (!excl && (v > bv || (v == bv && i < bi))) { bv = v; bi = i; }
      }
      sv[tid] = bv; si[tid] = bi;
      __syncthreads();
      for (int off = 128; off > 0; off >>= 1) {
        if (tid < off) {
          float b = sv[tid+off]; int ib = si[tid+off];
          if (b > sv[tid] || (b == sv[tid] && ib < si[tid])) { sv[tid] = b; si[tid] = ib; }
        }
        __syncthreads();
      }
      if (tid == 0) {
        int w = si[0];
        chosen[r] = w;
        idx5[r] = w;                       // kernel-boundary flush covers these
        wsc[r] = 1.0f / (1.0f + ages[w] * 0.01f);
      }
      __syncthreads();
    }
  }
}

// ---------------- pre-projection (R6 winner, unchanged) ----------------
__global__ __launch_bounds__(256) void k_pre(
    const float* __restrict__ ep, const float* __restrict__ x1,
    const int* __restrict__ idx5, const float* __restrict__ wsc,
    const float* __restrict__ wihF, const float* __restrict__ wihB,
    const float* __restrict__ bihF, const float* __restrict__ bhhF,
    const float* __restrict__ bihB, const float* __restrict__ bhhB,
    float* __restrict__ pre) {
  int t = blockIdx.x, dir = blockIdx.y;
  int tid = threadIdx.x;                 // 256 threads
  __shared__ __align__(16) float xs[5*512];
  if (ep) {
    for (int f = tid; f < 5*512; f += 256) {
      int b = f >> 9, i = f & 511;
      xs[f] = ep[((size_t)idx5[b]*LL + t)*DD + i] * wsc[b];
    }
  } else {
    for (int f = tid; f < 5*512; f += 256) {
      int b = f >> 9, i = f & 511;
      xs[f] = x1[((size_t)b*LL + t)*DD + i];
    }
  }
  const float* wih = dir ? wihB : wihF;
  const float* bih = dir ? bihB : bihF;
  const float* bhh = dir ? bhhB : bhhF;
  __syncthreads();

  const float4* w4 = (const float4*)wih;       // row stride = 128 quads
  const float4* x4 = (const float4*)xs;        // b stride = 128 quads
  float acc[4][5];
  #pragma unroll
  for (int g = 0; g < 4; ++g)
    #pragma unroll
    for (int b = 0; b < 5; ++b) acc[g][b] = 0.f;

  #pragma unroll 4
  for (int kq = 0; kq < 128; ++kq) {
    float4 xv[5];
    #pragma unroll
    for (int b = 0; b < 5; ++b) xv[b] = x4[b*128 + kq];
    #pragma unroll
    for (int g = 0; g < 4; ++g) {
      float4 w = w4[(size_t)(tid + g*256)*128 + kq];
      #pragma unroll
      for (int b = 0; b < 5; ++b) {
        acc[g][b] += w.x*xv[b].x + w.y*xv[b].y + w.z*xv[b].z + w.w*xv[b].w;
      }
    }
  }

  size_t pbase = (((size_t)dir*LL + t)*5)*1024;
  #pragma unroll
  for (int g = 0; g < 4; ++g) {
    int row = tid + g*256;
    float bias = bih[row] + bhh[row];
    #pragma unroll
    for (int b = 0; b < 5; ++b)
      pre[pbase + (size_t)b*1024 + row] = acc[g][b] + bias;
  }
}

// ---------------- persistent bidirectional LSTM layer (R7 champion, frozen) ----------------
__global__ __launch_bounds__(1024) void k_lstm(
    const float* __restrict__ whhF, const float* __restrict__ whhB,
    const float* __restrict__ pre, float* __restrict__ out,
    float* __restrict__ hg, int* __restrict__ flg) {
  int wg  = blockIdx.x;
  int dir = wg >> 3;
  int q   = wg & 7;                       // unit chunk: units [q*32, q*32+32)
  int tid = threadIdx.x;
  int rp  = tid & 63;                     // row pair: local gate rows 2rp, 2rp+1
  int jq  = tid >> 6;                     // 0..15
  int jb  = jq * 16;
  const float* whh = dir ? whhB : whhF;

  __shared__ __align__(16) float h_lds[5*256];
  __shared__ __align__(16) float part[5*16*130];   // [b][jq][130]
  __shared__ float c_s[5*32];
  __shared__ float pre_lds[5*128];

  int r0 = 2*rp, r1 = 2*rp + 1;
  int gr0 = (r0 >> 5)*256 + q*32 + (r0 & 31);
  int gr1 = (r1 >> 5)*256 + q*32 + (r1 & 31);
  float w0[16], w1[16];
  #pragma unroll
  for (int m4 = 0; m4 < 4; ++m4) {
    float4 a = *(const float4*)(whh + (size_t)gr0*256 + jb + m4*4);
    w0[m4*4+0]=a.x; w0[m4*4+1]=a.y; w0[m4*4+2]=a.z; w0[m4*4+3]=a.w;
    float4 c = *(const float4*)(whh + (size_t)gr1*256 + jb + m4*4);
    w1[m4*4+0]=c.x; w1[m4*4+1]=c.y; w1[m4*4+2]=c.z; w1[m4*4+3]=c.w;
  }
  for (int f = tid; f < 1280; f += 1024) h_lds[f] = 0.f;
  if (tid < 160) c_s[tid] = 0.f;
  float* hg_dir = hg + (size_t)dir * 2 * 1280;
  int*  flg_dir = flg + dir * 64;
  __syncthreads();

  for (int s = 0; s < LL; ++s) {
    int t = dir ? (LL-1-s) : s;
    if (tid < 640) {
      int b = tid >> 7, r = tid & 127;
      int grow = (r >> 5)*256 + q*32 + (r & 31);
      pre_lds[tid] = pre[(((size_t)dir*LL + t)*5 + b)*1024 + grow];
    }
    if (s > 0) {
      const float* hrd = hg_dir + (size_t)(s & 1) * 1280;
      if (tid < 8) {
        while (__hip_atomic_load(&flg_dir[tid], __ATOMIC_RELAXED,
                                 __HIP_MEMORY_SCOPE_AGENT) < s) {}
      }
      __syncthreads();
      for (int f = tid; f < 1120; f += 1024) {
        int b = f / 224, w2 = f % 224;
        int c7 = w2 >> 5, u = w2 & 31;
        int pch = c7 + (c7 >= q);
        int idx = b*256 + pch*32 + u;
        h_lds[idx] = __hip_atomic_load(&hrd[idx], __ATOMIC_RELAXED,
                                       __HIP_MEMORY_SCOPE_AGENT);
      }
    }
    __syncthreads();
    {
      float acc0[5], acc1[5];
      #pragma unroll
      for (int b = 0; b < 5; ++b) {
        const float4* h4 = (const float4*)&h_lds[b*256 + jb];
        float a0 = 0.f, a1 = 0.f;
        #pragma unroll
        for (int m4 = 0; m4 < 4; ++m4) {
          float4 hv = h4[m4];
          a0 += w0[m4*4+0]*hv.x + w0[m4*4+1]*hv.y + w0[m4*4+2]*hv.z + w0[m4*4+3]*hv.w;
          a1 += w1[m4*4+0]*hv.x + w1[m4*4+1]*hv.y + w1[m4*4+2]*hv.z + w1[m4*4+3]*hv.w;
        }
        acc0[b] = a0; acc1[b] = a1;
      }
      #pragma unroll
      for (int b = 0; b < 5; ++b) {
        *(float2*)&part[(b*16 + jq)*130 + 2*rp] = make_float2(acc0[b], acc1[b]);
      }
    }
    __syncthreads();
    if (tid < 160) {
      int b = tid >> 5, u = tid & 31;
      float g[4];
      #pragma unroll
      for (int gate = 0; gate < 4; ++gate) {
        int r = gate*32 + u;
        float sum = pre_lds[b*128 + r];
        #pragma unroll
        for (int m = 0; m < 16; ++m) sum += part[(b*16 + m)*130 + r];
        g[gate] = sum;
      }
      float ig = sigf(g[0]), fg = sigf(g[1]), cc = tanhf(g[2]), og = sigf(g[3]);
      float cn = fg * c_s[b*32 + u] + ig * cc;
      c_s[b*32 + u] = cn;
      float hv = og * tanhf(cn);
      out[((size_t)b*LL + t)*DD + dir*HH + q*32 + u] = hv;
      h_lds[b*256 + q*32 + u] = hv;
      float* hwr = hg_dir + (size_t)((s + 1) & 1) * 1280;
      __hip_atomic_store(&hwr[b*256 + q*32 + u], hv,
                         __ATOMIC_RELAXED, __HIP_MEMORY_SCOPE_AGENT);
    }
    __syncthreads();
    if (tid == 0)
      __hip_atomic_store(&flg_dir[q], s + 1, __ATOMIC_RELAXED,
                         __HIP_MEMORY_SCOPE_AGENT);
  }
}

// ---------------- attention epilogue ----------------
__global__ void k_attn(const float* __restrict__ out1, const float* __restrict__ csb,
                       float* __restrict__ outp) {
  int b = blockIdx.x, tid = threadIdx.x;   // 5 blocks x 256 threads
  __shared__ float cs[512];
  __shared__ float att[128];
  __shared__ float red[256];
  __shared__ float smax, ssum;
  cs[tid] = csb[tid]; cs[tid+256] = csb[tid+256];
  __syncthreads();
  {
    int t = tid & 127, half = tid >> 7;
    const float* row = out1 + ((size_t)b*LL + t)*DD + half*256;
    const float* c2 = cs + half*256;
    float a = 0.f;
    for (int d = 0; d < 256; ++d) a += row[d] * c2[d];
    red[tid] = a;
  }
  __syncthreads();
  if (tid < 128) att[tid] = red[tid] + red[tid+128];
  __syncthreads();
  if (tid < 64) red[tid] = fmaxf(att[tid], att[tid+64]);
  __syncthreads();
  if (tid == 0) { float m = red[0]; for (int o = 1; o < 64; ++o) m = fmaxf(m, red[o]); smax = m; }
  __syncthreads();
  if (tid < 128) att[tid] = expf(att[tid] - smax);
  __syncthreads();
  if (tid < 64) red[tid] = att[tid] + att[tid+64];
  __syncthreads();
  if (tid == 0) { float s = 0.f; for (int o = 0; o < 64; ++o) s += red[o]; ssum = s; }
  __syncthreads();
  float inv = 1.0f / ssum;
  for (int d = tid; d < DD; d += 256) {
    float acc = 0.f;
    for (int t2 = 0; t2 < LL; ++t2) acc += att[t2] * out1[((size_t)b*LL + t2)*DD + d];
    outp[b*DD + d] = acc * inv;
  }
}

extern "C" void kernel_launch(void* const* d_in, const int* in_sizes, int n_in,
                              void* d_out, int out_size, void* d_ws, size_t ws_size,
                              hipStream_t stream) {
  (void)in_sizes; (void)n_in; (void)out_size; (void)ws_size;
  const float* ep   = (const float*)d_in[0];
  const float* qu   = (const float*)d_in[1];
  const float* cst  = (const float*)d_in[2];
  const float* ages = (const float*)d_in[3];
  const float* Wq   = (const float*)d_in[4];
  const float* bq   = (const float*)d_in[5];
  const float* Wk   = (const float*)d_in[6];
  const float* bk   = (const float*)d_in[7];
  const float *wih[4], *whh[4], *bih[4], *bhh[4];
  for (int l = 0; l < 4; ++l) {
    wih[l] = (const float*)d_in[8 + l*4 + 0];
    whh[l] = (const float*)d_in[8 + l*4 + 1];
    bih[l] = (const float*)d_in[8 + l*4 + 2];
    bhh[l] = (const float*)d_in[8 + l*4 + 3];
  }
  char* ws = (char*)d_ws;
  float* qp   = (float*)(ws + OFF_QP);
  float* uvec = (float*)(ws + OFF_U);
  float* cc   = (float*)(ws + OFF_CC);
  float* sc   = (float*)(ws + OFF_SC);
  float* wsc  = (float*)(ws + OFF_WSC);
  int*   idx5 = (int*)  (ws + OFF_IDX);
  float* hg0  = (float*)(ws + OFF_HG);
  float* hg1  = (float*)(ws + OFF_HG + 20480);
  int*   flg0 = (int*)  (ws + OFF_FLG0);
  int*   flg1 = (int*)  (ws + OFF_FLG1);
  int*   cnt  = (int*)  (ws + OFF_CNT);
  float* pre  = (float*)(ws + OFF_PRE);
  float* out0 = (float*)(ws + OFF_OUT0);
  float* out1 = (float*)(ws + OFF_OUT1);

  // zero flags (both layers) + front-end counters in one memset
  (void)hipMemsetAsync(ws + OFF_FLG0, 0, 12288, stream);

  k_front<<<NN, 256, 0, stream>>>(Wq, qu, bq, Wk, bk, ep, ages,
                                  qp, uvec, cc, sc, idx5, wsc, cnt);

  k_pre <<<dim3(LL,2), 256, 0, stream>>>(ep, nullptr, idx5, wsc,
        wih[0], wih[1], bih[0], bhh[0], bih[1], bhh[1], pre);
  k_lstm<<<16, 1024, 0, stream>>>(whh[0], whh[1], pre, out0, hg0, flg0);

  k_pre <<<dim3(LL,2), 256, 0, stream>>>(nullptr, out0, idx5, wsc,
        wih[2], wih[3], bih[2], bhh[2], bih[3], bhh[3], pre);
  k_lstm<<<16, 1024, 0, stream>>>(whh[2], whh[3], pre, out1, hg1, flg1);

  k_attn<<<KK, 256, 0, stream>>>(out1, cst, (float*)d_out);
}